// Round 5
// baseline (471.422 us; speedup 1.0000x reference)
//
#include <hip/hip_runtime.h>
#include <hip/hip_bf16.h>

#define N_NODES_C 100000
#define N_PAD_C   100096   // padded to multiple of 128 for k1 tiles
#define N_RELS_C  237
#define N_EDGES_C 500000
#define D 128

typedef __attribute__((ext_vector_type(8))) short short8;
typedef __attribute__((ext_vector_type(4))) float f32x4;

__device__ __forceinline__ ushort f2bf(float x) {
    union { float f; uint u; } v; v.f = x;
    uint r = v.u + 0x7FFFu + ((v.u >> 16) & 1u);   // RNE
    return (ushort)(r >> 16);
}
__device__ __forceinline__ float bf2f_hi(uint u) {  // bits already in high half
    union { uint u; float f; } v; v.u = u; return v.f;
}

// ============ K0: fuse weights =============
// WfTb[j][k]   (j<128)  = sum_i W_ent[k][i] * W_ent2[i][j]      (A path, bf16, transposed)
// WfTb[128+j][k]        = sum_i W_ent[k][i] * W_ent2[128+i][j]  (B path)
// WR[k][j]              = sum_i W_rel[k][i] * W_ent2[256+i][j]
// biasC[j] = b_ent@(W1+W2) + b_rel@W3 + b_ent2
__global__ void k_fuse_w(const float* __restrict__ W_ent, const float* __restrict__ W_rel,
                         const float* __restrict__ W_ent2,
                         const float* __restrict__ b_ent, const float* __restrict__ b_rel,
                         const float* __restrict__ b_ent2,
                         float* __restrict__ WR, ushort* __restrict__ WfTb,
                         float* __restrict__ biasC) {
    int j = threadIdx.x;       // 0..127 output col
    int k = blockIdx.x;        // 0..127 row
    int which = blockIdx.y;    // 0..3
    if (which == 0) {
        float acc = 0.f;
        for (int i = 0; i < D; ++i) acc += W_ent[k*D+i] * W_ent2[i*D+j];
        WfTb[j*D + k] = f2bf(acc);
    } else if (which == 1) {
        float acc = 0.f;
        for (int i = 0; i < D; ++i) acc += W_ent[k*D+i] * W_ent2[(D+i)*D+j];
        WfTb[(D+j)*D + k] = f2bf(acc);
    } else if (which == 2) {
        float acc = 0.f;
        for (int i = 0; i < D; ++i) acc += W_rel[k*D+i] * W_ent2[(2*D+i)*D+j];
        WR[k*D + j] = acc;
    } else if (k == 0) {
        float acc = b_ent2[j];
        for (int i = 0; i < D; ++i) {
            acc += b_ent[i] * (W_ent2[i*D+j] + W_ent2[(D+i)*D+j]);
            acc += b_rel[i] * W_ent2[(2*D+i)*D+j];
        }
        biasC[j] = acc;
    }
}

// ============ K0b: relation table + rel/const attention scalars =============
__global__ void k_rel_scalars(const float* __restrict__ rel_embed,
                              const float* __restrict__ a_w, const float* __restrict__ a_b,
                              const float* __restrict__ WR, const float* __restrict__ biasC,
                              float* __restrict__ Rm, float* __restrict__ sR,
                              float* __restrict__ sConst) {
    int j = threadIdx.x;   // 128 threads
    int b = blockIdx.x;    // 0..237
    __shared__ float red[128];
    if (b < N_RELS_C) {
        float acc = 0.f;
        for (int k = 0; k < D; ++k) acc += rel_embed[b*D+k] * WR[k*D+j];
        Rm[b*D+j] = acc;
        red[j] = acc * a_w[j];
        __syncthreads();
        for (int s = 64; s > 0; s >>= 1) { if (j < s) red[j] += red[j+s]; __syncthreads(); }
        if (j == 0) sR[b] = red[0];
    } else {
        red[j] = biasC[j] * a_w[j];
        __syncthreads();
        for (int s = 64; s > 0; s >>= 1) { if (j < s) red[j] += red[j+s]; __syncthreads(); }
        if (j == 0) sConst[0] = red[0] + a_b[0];
    }
}

// ============ K1: MFMA node GEMM + fused prep =============
// [An|Bn] = ent(100000x128 fp32 -> bf16 in-register) @ WfT(256x128 bf16), fp32 acc.
// A-half stored fp32 DIRECTLY INTO h (d_out); B-half bf16 into BnB.
// Epilogue also computes sA[n] = A[n]@a_w, sB[n] = B[n]@a_w (replaces k_prep).
// LDS holds only W (64 KB, XOR-swizzled); single __syncthreads after staging.
__global__ __launch_bounds__(256) void k1_mfma(const float* __restrict__ ent,
                                               const ushort* __restrict__ WfTb,
                                               const float* __restrict__ a_w,
                                               float* __restrict__ h,
                                               ushort* __restrict__ BnB,
                                               float* __restrict__ sA,
                                               float* __restrict__ sB,
                                               int n_nodes) {
    __shared__ __align__(16) ushort wL[256*128];   // 64 KB
    int tid = threadIdx.x;
    int m0 = blockIdx.x * 128;

    // stage W: 256 rows x 16 (16B units), swizzled unit col = k16 ^ (r&15)
#pragma unroll
    for (int u = 0; u < 16; ++u) {
        int f = u*256 + tid;          // 0..4095
        int r = f >> 4, k16 = f & 15;
        *(uint4*)&wL[r*128 + ((k16 ^ (r & 15)) << 3)] =
            *(const uint4*)&WfTb[r*128 + (k16 << 3)];
    }
    __syncthreads();

    int wave = tid >> 6, lane = tid & 63;
    int q = lane >> 4, c = lane & 15;
    int wm = wave * 32;                 // 4 waves x 32 rows = 128 rows

    f32x4 acc[2][16];
#pragma unroll
    for (int mt = 0; mt < 2; ++mt)
#pragma unroll
        for (int nt = 0; nt < 16; ++nt) { f32x4 z = {0.f,0.f,0.f,0.f}; acc[mt][nt] = z; }

#pragma unroll
    for (int chunk = 0; chunk < 4; ++chunk) {
        int k16 = chunk*4 + q;
        short8 a[2];
#pragma unroll
        for (int mt = 0; mt < 2; ++mt) {
            int row = m0 + wm + mt*16 + c;
            float4 e0 = make_float4(0.f,0.f,0.f,0.f), e1 = e0;
            if (row < n_nodes) {
                const float* ep = &ent[(size_t)row*D + (k16 << 3)];
                e0 = *(const float4*)ep;
                e1 = *(const float4*)(ep + 4);
            }
            short8 pk;
            pk[0]=(short)f2bf(e0.x); pk[1]=(short)f2bf(e0.y); pk[2]=(short)f2bf(e0.z); pk[3]=(short)f2bf(e0.w);
            pk[4]=(short)f2bf(e1.x); pk[5]=(short)f2bf(e1.y); pk[6]=(short)f2bf(e1.z); pk[7]=(short)f2bf(e1.w);
            a[mt] = pk;
        }
#pragma unroll
        for (int nt = 0; nt < 16; ++nt) {
            int row = nt*16 + c;
            short8 b = *(const short8*)&wL[row*128 + ((k16 ^ c) << 3)];
            acc[0][nt] = __builtin_amdgcn_mfma_f32_16x16x32_bf16(a[0], b, acc[0][nt], 0, 0, 0);
            acc[1][nt] = __builtin_amdgcn_mfma_f32_16x16x32_bf16(a[1], b, acc[1][nt], 0, 0, 0);
        }
    }

    // a_w values this lane needs for the sA/sB reduction: col = nt*16 + c
    float aw[8];
#pragma unroll
    for (int nt = 0; nt < 8; ++nt) aw[nt] = a_w[nt*16 + c];

    // epilogue: C/D layout col=lane&15, row=q*4+reg
#pragma unroll
    for (int mt = 0; mt < 2; ++mt) {
#pragma unroll
        for (int reg = 0; reg < 4; ++reg) {
            int m = m0 + wm + mt*16 + q*4 + reg;
            float pa = 0.f, pb = 0.f;
#pragma unroll
            for (int nt = 0; nt < 8; ++nt) {
                pa += acc[mt][nt][reg]   * aw[nt];
                pb += acc[mt][nt+8][reg] * aw[nt];
            }
#pragma unroll
            for (int msk = 1; msk < 16; msk <<= 1) {
                pa += __shfl_xor(pa, msk);
                pb += __shfl_xor(pb, msk);
            }
            if (m < n_nodes) {
                if (c == 0) { sA[m] = pa; sB[m] = pb; }
#pragma unroll
                for (int nt = 0; nt < 16; ++nt) {
                    int col = nt*16 + c;
                    float v = acc[mt][nt][reg];
                    if (col < D) h[(size_t)m*D + col] = v;
                    else         BnB[(size_t)m*D + (col - D)] = f2bf(v);
                }
            }
        }
    }
}

// ============ K2: CSR build =============
__global__ void k_hist(const int* __restrict__ trip, int* __restrict__ deg, int n_edges) {
    int e = blockIdx.x*256 + threadIdx.x;
    if (e >= n_edges) return;
    int s = trip[3*e];
    if ((unsigned)s >= (unsigned)N_NODES_C) return;   // guard (no-op on valid input)
    atomicAdd(&deg[s], 1);
}

// single-block full exclusive scan: off/cursor from deg, off[n]=total
__global__ __launch_bounds__(1024) void k_scan_all(const int* __restrict__ deg,
                                                   int* __restrict__ off,
                                                   int* __restrict__ cursor,
                                                   int n, int total_edges) {
    __shared__ int s[1024];
    int t = threadIdx.x;
    const int per = (n + 1023) / 1024;   // 98
    int base = t * per;
    int lim = n - base; if (lim < 0) lim = 0; if (lim > per) lim = per;
    int sum = 0;
    for (int i = 0; i < lim; ++i) sum += deg[base + i];
    s[t] = sum; __syncthreads();
    int v = sum;
    for (int d = 1; d < 1024; d <<= 1) {
        int u = (t >= d) ? s[t - d] : 0;
        __syncthreads();
        s[t] += u;
        __syncthreads();
    }
    int run = s[t] - v;   // exclusive prefix of this thread's range
    for (int i = 0; i < lim; ++i) {
        int dv = deg[base + i];
        off[base + i] = run;
        cursor[base + i] = run;
        run += dv;
    }
    if (t == 0) off[n] = total_edges;
}

// ============ K2c: per-edge b + scatter combined (key,b) record into CSR slot ======
__global__ void k_edge_b(const int* __restrict__ trip, const float* __restrict__ sA,
                         const float* __restrict__ sB, const float* __restrict__ sR,
                         const float* __restrict__ sConst, int* __restrict__ cursor,
                         uint2* __restrict__ kb, int n_edges) {
    int e = blockIdx.x*256 + threadIdx.x;
    if (e >= n_edges) return;
    int s = trip[3*e], d = trip[3*e+1], r = trip[3*e+2];
    if ((unsigned)s >= (unsigned)N_NODES_C || (unsigned)d >= (unsigned)N_NODES_C ||
        (unsigned)r >= (unsigned)N_RELS_C) return;   // guard (matches k_hist)
    float logit = sA[s] + sB[d] + sR[r] + sConst[0];
    float l = logit > 0.f ? logit : 0.01f*logit;
    float b = expf(l);
    int p = atomicAdd(&cursor[s], 1);
    kb[p] = make_uint2((uint)(d | (r << 20)), __float_as_uint(b));
}

// ============ K3: node-major aggregation (no atomics), unroll-4 gathers =============
// h already holds An (fp32). h[n] = An + biasC + sum alpha*(B[dst]+R[rel]);
// zero-degree nodes overwritten with 0 (segment_sum over empty set).
__global__ void k_aggregate(const int* __restrict__ off, const uint2* __restrict__ kb,
                            const ushort* __restrict__ BnB, const float* __restrict__ Rm,
                            const float* __restrict__ biasC, float* __restrict__ h,
                            int n_nodes) {
    int g = threadIdx.x >> 5, lane = threadIdx.x & 31;
    int n = blockIdx.x*8 + g;
    if (n >= n_nodes) return;
    int o0 = off[n], o1 = off[n+1];
    int c = lane*4;
    if (o0 == o1) {
        *(float4*)&h[(size_t)n*D + c] = make_float4(0.f,0.f,0.f,0.f);
        return;
    }
    float s = 0.f;
    for (int p = o0 + lane; p < o1; p += 32) s += __uint_as_float(kb[p].y);
    for (int m = 16; m > 0; m >>= 1) s += __shfl_xor(s, m, 32);
    float inv = 1.f / s;
    float4 acc = *(const float4*)&h[(size_t)n*D + c];     // An (fp32)
    float4 bc  = *(const float4*)&biasC[c];
    acc.x += bc.x; acc.y += bc.y; acc.z += bc.z; acc.w += bc.w;

    int p = o0;
    for (; p + 4 <= o1; p += 4) {
        uint2 kv0 = kb[p+0], kv1 = kb[p+1], kv2 = kb[p+2], kv3 = kb[p+3];
        uint2 g0 = *(const uint2*)&BnB[(size_t)(kv0.x & 0xFFFFF)*D + c];
        uint2 g1 = *(const uint2*)&BnB[(size_t)(kv1.x & 0xFFFFF)*D + c];
        uint2 g2 = *(const uint2*)&BnB[(size_t)(kv2.x & 0xFFFFF)*D + c];
        uint2 g3 = *(const uint2*)&BnB[(size_t)(kv3.x & 0xFFFFF)*D + c];
        float4 r0 = *(const float4*)&Rm[(kv0.x >> 20)*D + c];
        float4 r1 = *(const float4*)&Rm[(kv1.x >> 20)*D + c];
        float4 r2 = *(const float4*)&Rm[(kv2.x >> 20)*D + c];
        float4 r3 = *(const float4*)&Rm[(kv3.x >> 20)*D + c];
        float a0 = __uint_as_float(kv0.y) * inv;
        float a1 = __uint_as_float(kv1.y) * inv;
        float a2 = __uint_as_float(kv2.y) * inv;
        float a3 = __uint_as_float(kv3.y) * inv;
        acc.x += a0*(bf2f_hi(g0.x << 16)         + r0.x)
               + a1*(bf2f_hi(g1.x << 16)         + r1.x)
               + a2*(bf2f_hi(g2.x << 16)         + r2.x)
               + a3*(bf2f_hi(g3.x << 16)         + r3.x);
        acc.y += a0*(bf2f_hi(g0.x & 0xFFFF0000u) + r0.y)
               + a1*(bf2f_hi(g1.x & 0xFFFF0000u) + r1.y)
               + a2*(bf2f_hi(g2.x & 0xFFFF0000u) + r2.y)
               + a3*(bf2f_hi(g3.x & 0xFFFF0000u) + r3.y);
        acc.z += a0*(bf2f_hi(g0.y << 16)         + r0.z)
               + a1*(bf2f_hi(g1.y << 16)         + r1.z)
               + a2*(bf2f_hi(g2.y << 16)         + r2.z)
               + a3*(bf2f_hi(g3.y << 16)         + r3.z);
        acc.w += a0*(bf2f_hi(g0.y & 0xFFFF0000u) + r0.w)
               + a1*(bf2f_hi(g1.y & 0xFFFF0000u) + r1.w)
               + a2*(bf2f_hi(g2.y & 0xFFFF0000u) + r2.w)
               + a3*(bf2f_hi(g3.y & 0xFFFF0000u) + r3.w);
    }
    for (; p < o1; ++p) {
        uint2 kv = kb[p];
        float al = __uint_as_float(kv.y) * inv;
        uint2 braw = *(const uint2*)&BnB[(size_t)(kv.x & 0xFFFFF)*D + c];
        float4 rv  = *(const float4*)&Rm[(kv.x >> 20)*D + c];
        acc.x += al*(bf2f_hi(braw.x << 16)         + rv.x);
        acc.y += al*(bf2f_hi(braw.x & 0xFFFF0000u) + rv.y);
        acc.z += al*(bf2f_hi(braw.y << 16)         + rv.z);
        acc.w += al*(bf2f_hi(braw.y & 0xFFFF0000u) + rv.w);
    }
    *(float4*)&h[(size_t)n*D + c] = acc;
}

extern "C" void kernel_launch(void* const* d_in, const int* in_sizes, int n_in,
                              void* d_out, int out_size, void* d_ws, size_t ws_size,
                              hipStream_t stream) {
    const int*   trip   = (const int*)  d_in[0];
    const float* ent    = (const float*)d_in[1];
    const float* relE   = (const float*)d_in[2];
    const float* W_ent  = (const float*)d_in[3];
    const float* b_ent  = (const float*)d_in[4];
    const float* W_rel  = (const float*)d_in[5];
    const float* b_rel  = (const float*)d_in[6];
    const float* W_ent2 = (const float*)d_in[7];
    const float* b_ent2 = (const float*)d_in[8];
    const float* a_w    = (const float*)d_in[9];
    const float* a_b    = (const float*)d_in[10];
    float* h = (float*)d_out;

    // Workspace: ~31.5 MB total (proven-safe ceiling is the 57.6 MB of round 4;
    // round 3's 83.26 MB overran d_ws — keep footprint well below).
    char* ws = (char*)d_ws;
    size_t o = 0;
    auto alloc = [&](size_t bytes) { size_t p = o; o += (bytes + 255) & ~(size_t)255; return p; };
    float*  WR     = (float*) (ws + alloc(128*128*4));
    ushort* WfTb   = (ushort*)(ws + alloc(256*128*2));
    float*  biasC  = (float*) (ws + alloc(128*4));
    float*  Rm     = (float*) (ws + alloc((size_t)N_RELS_C*128*4));
    float*  sR     = (float*) (ws + alloc(N_RELS_C*4));
    float*  sConst = (float*) (ws + alloc(4));
    float*  sA     = (float*) (ws + alloc((size_t)N_NODES_C*4));
    float*  sB     = (float*) (ws + alloc((size_t)N_NODES_C*4));
    int*    deg    = (int*)   (ws + alloc((size_t)N_NODES_C*4));
    int*    off    = (int*)   (ws + alloc(((size_t)N_NODES_C+1)*4));
    int*    cursor = (int*)   (ws + alloc((size_t)N_NODES_C*4));
    uint2*  kb     = (uint2*) (ws + alloc((size_t)N_EDGES_C*8));
    ushort* BnB    = (ushort*)(ws + alloc((size_t)N_PAD_C*128*2));

    hipMemsetAsync(deg, 0, (size_t)N_NODES_C*4, stream);

    k_fuse_w<<<dim3(128,4), 128, 0, stream>>>(W_ent, W_rel, W_ent2, b_ent, b_rel, b_ent2,
                                              WR, WfTb, biasC);
    k_rel_scalars<<<N_RELS_C+1, 128, 0, stream>>>(relE, a_w, a_b, WR, biasC,
                                                  Rm, sR, sConst);
    k1_mfma<<<N_PAD_C/128, 256, 0, stream>>>(ent, WfTb, a_w, h, BnB, sA, sB, N_NODES_C);
    k_hist<<<(N_EDGES_C+255)/256, 256, 0, stream>>>(trip, deg, N_EDGES_C);
    k_scan_all<<<1, 1024, 0, stream>>>(deg, off, cursor, N_NODES_C, N_EDGES_C);
    k_edge_b<<<(N_EDGES_C+255)/256, 256, 0, stream>>>(trip, sA, sB, sR, sConst,
                                                      cursor, kb, N_EDGES_C);
    k_aggregate<<<(N_NODES_C+7)/8, 256, 0, stream>>>(off, kb, BnB, Rm, biasC,
                                                     h, N_NODES_C);
}

// Round 6
// 257.157 us; speedup vs baseline: 1.8332x; 1.8332x over previous
//
#include <hip/hip_runtime.h>
#include <hip/hip_bf16.h>

#define N_NODES_C 100000
#define N_PAD_C   100096   // padded to multiple of 128 for k1 tiles
#define N_RELS_C  237
#define N_EDGES_C 500000
#define D 128

typedef __attribute__((ext_vector_type(8))) short short8;
typedef __attribute__((ext_vector_type(4))) float f32x4;

__device__ __forceinline__ ushort f2bf(float x) {
    union { float f; uint u; } v; v.f = x;
    uint r = v.u + 0x7FFFu + ((v.u >> 16) & 1u);   // RNE
    return (ushort)(r >> 16);
}
__device__ __forceinline__ float bf2f_hi(uint u) {  // bits already in high half
    union { uint u; float f; } v; v.u = u; return v.f;
}

// ============ K0: fuse weights =============
// WfTb[j][k]   (j<128)  = sum_i W_ent[k][i] * W_ent2[i][j]      (A path, bf16, transposed)
// WfTb[128+j][k]        = sum_i W_ent[k][i] * W_ent2[128+i][j]  (B path)
// WR[k][j]              = sum_i W_rel[k][i] * W_ent2[256+i][j]
// biasC[j] = b_ent@(W1+W2) + b_rel@W3 + b_ent2
__global__ void k_fuse_w(const float* __restrict__ W_ent, const float* __restrict__ W_rel,
                         const float* __restrict__ W_ent2,
                         const float* __restrict__ b_ent, const float* __restrict__ b_rel,
                         const float* __restrict__ b_ent2,
                         float* __restrict__ WR, ushort* __restrict__ WfTb,
                         float* __restrict__ biasC) {
    int j = threadIdx.x;       // 0..127 output col
    int k = blockIdx.x;        // 0..127 row
    int which = blockIdx.y;    // 0..3
    if (which == 0) {
        float acc = 0.f;
        for (int i = 0; i < D; ++i) acc += W_ent[k*D+i] * W_ent2[i*D+j];
        WfTb[j*D + k] = f2bf(acc);
    } else if (which == 1) {
        float acc = 0.f;
        for (int i = 0; i < D; ++i) acc += W_ent[k*D+i] * W_ent2[(D+i)*D+j];
        WfTb[(D+j)*D + k] = f2bf(acc);
    } else if (which == 2) {
        float acc = 0.f;
        for (int i = 0; i < D; ++i) acc += W_rel[k*D+i] * W_ent2[(2*D+i)*D+j];
        WR[k*D + j] = acc;
    } else if (k == 0) {
        float acc = b_ent2[j];
        for (int i = 0; i < D; ++i) {
            acc += b_ent[i] * (W_ent2[i*D+j] + W_ent2[(D+i)*D+j]);
            acc += b_rel[i] * W_ent2[(2*D+i)*D+j];
        }
        biasC[j] = acc;
    }
}

// ============ K0b: relation table + rel/const attention scalars =============
__global__ void k_rel_scalars(const float* __restrict__ rel_embed,
                              const float* __restrict__ a_w, const float* __restrict__ a_b,
                              const float* __restrict__ WR, const float* __restrict__ biasC,
                              float* __restrict__ Rm, float* __restrict__ sR,
                              float* __restrict__ sConst) {
    int j = threadIdx.x;   // 128 threads
    int b = blockIdx.x;    // 0..237
    __shared__ float red[128];
    if (b < N_RELS_C) {
        float acc = 0.f;
        for (int k = 0; k < D; ++k) acc += rel_embed[b*D+k] * WR[k*D+j];
        Rm[b*D+j] = acc;
        red[j] = acc * a_w[j];
        __syncthreads();
        for (int s = 64; s > 0; s >>= 1) { if (j < s) red[j] += red[j+s]; __syncthreads(); }
        if (j == 0) sR[b] = red[0];
    } else {
        red[j] = biasC[j] * a_w[j];
        __syncthreads();
        for (int s = 64; s > 0; s >>= 1) { if (j < s) red[j] += red[j+s]; __syncthreads(); }
        if (j == 0) sConst[0] = red[0] + a_b[0];
    }
}

// ============ K1: MFMA node GEMM + fused prep =============
// [An|Bn] = ent(100000x128 fp32 -> bf16 in-register) @ WfT(256x128 bf16), fp32 acc.
// A-half stored fp32 DIRECTLY INTO h (d_out); B-half bf16 into BnB.
// Epilogue also computes sA[n] = A[n]@a_w, sB[n] = B[n]@a_w (replaces k_prep).
// LDS holds only W (64 KB, XOR-swizzled); single __syncthreads after staging.
__global__ __launch_bounds__(256) void k1_mfma(const float* __restrict__ ent,
                                               const ushort* __restrict__ WfTb,
                                               const float* __restrict__ a_w,
                                               float* __restrict__ h,
                                               ushort* __restrict__ BnB,
                                               float* __restrict__ sA,
                                               float* __restrict__ sB,
                                               int n_nodes) {
    __shared__ __align__(16) ushort wL[256*128];   // 64 KB
    int tid = threadIdx.x;
    int m0 = blockIdx.x * 128;

    // stage W: 256 rows x 16 (16B units), swizzled unit col = k16 ^ (r&15)
#pragma unroll
    for (int u = 0; u < 16; ++u) {
        int f = u*256 + tid;          // 0..4095
        int r = f >> 4, k16 = f & 15;
        *(uint4*)&wL[r*128 + ((k16 ^ (r & 15)) << 3)] =
            *(const uint4*)&WfTb[r*128 + (k16 << 3)];
    }
    __syncthreads();

    int wave = tid >> 6, lane = tid & 63;
    int q = lane >> 4, c = lane & 15;
    int wm = wave * 32;                 // 4 waves x 32 rows = 128 rows

    f32x4 acc[2][16];
#pragma unroll
    for (int mt = 0; mt < 2; ++mt)
#pragma unroll
        for (int nt = 0; nt < 16; ++nt) { f32x4 z = {0.f,0.f,0.f,0.f}; acc[mt][nt] = z; }

#pragma unroll
    for (int chunk = 0; chunk < 4; ++chunk) {
        int k16 = chunk*4 + q;
        short8 a[2];
#pragma unroll
        for (int mt = 0; mt < 2; ++mt) {
            int row = m0 + wm + mt*16 + c;
            float4 e0 = make_float4(0.f,0.f,0.f,0.f), e1 = e0;
            if (row < n_nodes) {
                const float* ep = &ent[(size_t)row*D + (k16 << 3)];
                e0 = *(const float4*)ep;
                e1 = *(const float4*)(ep + 4);
            }
            short8 pk;
            pk[0]=(short)f2bf(e0.x); pk[1]=(short)f2bf(e0.y); pk[2]=(short)f2bf(e0.z); pk[3]=(short)f2bf(e0.w);
            pk[4]=(short)f2bf(e1.x); pk[5]=(short)f2bf(e1.y); pk[6]=(short)f2bf(e1.z); pk[7]=(short)f2bf(e1.w);
            a[mt] = pk;
        }
#pragma unroll
        for (int nt = 0; nt < 16; ++nt) {
            int row = nt*16 + c;
            short8 b = *(const short8*)&wL[row*128 + ((k16 ^ c) << 3)];
            acc[0][nt] = __builtin_amdgcn_mfma_f32_16x16x32_bf16(a[0], b, acc[0][nt], 0, 0, 0);
            acc[1][nt] = __builtin_amdgcn_mfma_f32_16x16x32_bf16(a[1], b, acc[1][nt], 0, 0, 0);
        }
    }

    // a_w values this lane needs for the sA/sB reduction: col = nt*16 + c
    float aw[8];
#pragma unroll
    for (int nt = 0; nt < 8; ++nt) aw[nt] = a_w[nt*16 + c];

    // epilogue: C/D layout col=lane&15, row=q*4+reg
#pragma unroll
    for (int mt = 0; mt < 2; ++mt) {
#pragma unroll
        for (int reg = 0; reg < 4; ++reg) {
            int m = m0 + wm + mt*16 + q*4 + reg;
            float pa = 0.f, pb = 0.f;
#pragma unroll
            for (int nt = 0; nt < 8; ++nt) {
                pa += acc[mt][nt][reg]   * aw[nt];
                pb += acc[mt][nt+8][reg] * aw[nt];
            }
#pragma unroll
            for (int msk = 1; msk < 16; msk <<= 1) {
                pa += __shfl_xor(pa, msk);
                pb += __shfl_xor(pb, msk);
            }
            if (m < n_nodes) {
                if (c == 0) { sA[m] = pa; sB[m] = pb; }
#pragma unroll
                for (int nt = 0; nt < 16; ++nt) {
                    int col = nt*16 + c;
                    float v = acc[mt][nt][reg];
                    if (col < D) h[(size_t)m*D + col] = v;
                    else         BnB[(size_t)m*D + (col - D)] = f2bf(v);
                }
            }
        }
    }
}

// ============ K2: CSR build =============
__global__ void k_hist(const int* __restrict__ trip, int* __restrict__ deg, int n_edges) {
    int e = blockIdx.x*256 + threadIdx.x;
    if (e >= n_edges) return;
    int s = trip[3*e];
    if ((unsigned)s >= (unsigned)N_NODES_C) return;   // guard (no-op on valid input)
    atomicAdd(&deg[s], 1);
}

// hierarchical 3-kernel scan (round-4 proven: coalesced, ~5 us combined)
__global__ void k_scan1(const int* __restrict__ deg, int* __restrict__ off,
                        int* __restrict__ bsum, int n) {
    __shared__ int s[1024];
    int i = blockIdx.x*1024 + threadIdx.x;
    int v = (i < n) ? deg[i] : 0;
    s[threadIdx.x] = v; __syncthreads();
    for (int d = 1; d < 1024; d <<= 1) {
        int t = (threadIdx.x >= d) ? s[threadIdx.x - d] : 0;
        __syncthreads();
        s[threadIdx.x] += t;
        __syncthreads();
    }
    if (i < n) off[i] = s[threadIdx.x] - v;          // exclusive, pre-block-offset
    if (threadIdx.x == 1023) bsum[blockIdx.x] = s[1023];
}

__global__ void k_scan2(int* __restrict__ bsum, int nb) {
    __shared__ int s[128];
    int v = (threadIdx.x < nb) ? bsum[threadIdx.x] : 0;
    s[threadIdx.x] = v; __syncthreads();
    for (int d = 1; d < 128; d <<= 1) {
        int t = (threadIdx.x >= d) ? s[threadIdx.x - d] : 0;
        __syncthreads();
        s[threadIdx.x] += t;
        __syncthreads();
    }
    if (threadIdx.x < nb) bsum[threadIdx.x] = s[threadIdx.x] - v;  // exclusive, in-place
}

__global__ void k_scan3(int* __restrict__ off, int* __restrict__ cursor,
                        const int* __restrict__ bsum, int n, int total_edges) {
    int i = blockIdx.x*1024 + threadIdx.x;
    if (i < n) {
        int o = off[i] + bsum[blockIdx.x];
        off[i] = o;
        cursor[i] = o;
    }
    if (i == 0) off[n] = total_edges;
}

// ============ K2c: per-edge b + scatter combined (key,b) record into CSR slot ======
__global__ void k_edge_b(const int* __restrict__ trip, const float* __restrict__ sA,
                         const float* __restrict__ sB, const float* __restrict__ sR,
                         const float* __restrict__ sConst, int* __restrict__ cursor,
                         uint2* __restrict__ kb, int n_edges) {
    int e = blockIdx.x*256 + threadIdx.x;
    if (e >= n_edges) return;
    int s = trip[3*e], d = trip[3*e+1], r = trip[3*e+2];
    if ((unsigned)s >= (unsigned)N_NODES_C || (unsigned)d >= (unsigned)N_NODES_C ||
        (unsigned)r >= (unsigned)N_RELS_C) return;   // guard (matches k_hist)
    float logit = sA[s] + sB[d] + sR[r] + sConst[0];
    float l = logit > 0.f ? logit : 0.01f*logit;
    float b = expf(l);
    int p = atomicAdd(&cursor[s], 1);
    kb[p] = make_uint2((uint)(d | (r << 20)), __float_as_uint(b));
}

// ============ K3: node-major aggregation (no atomics), unroll-4 gathers =============
// h already holds An (fp32). h[n] = An + biasC + sum alpha*(B[dst]+R[rel]);
// zero-degree nodes overwritten with 0 (segment_sum over empty set).
__global__ void k_aggregate(const int* __restrict__ off, const uint2* __restrict__ kb,
                            const ushort* __restrict__ BnB, const float* __restrict__ Rm,
                            const float* __restrict__ biasC, float* __restrict__ h,
                            int n_nodes) {
    int g = threadIdx.x >> 5, lane = threadIdx.x & 31;
    int n = blockIdx.x*8 + g;
    if (n >= n_nodes) return;
    int o0 = off[n], o1 = off[n+1];
    int c = lane*4;
    if (o0 == o1) {
        *(float4*)&h[(size_t)n*D + c] = make_float4(0.f,0.f,0.f,0.f);
        return;
    }
    float s = 0.f;
    for (int p = o0 + lane; p < o1; p += 32) s += __uint_as_float(kb[p].y);
    for (int m = 16; m > 0; m >>= 1) s += __shfl_xor(s, m, 32);
    float inv = 1.f / s;
    float4 acc = *(const float4*)&h[(size_t)n*D + c];     // An (fp32)
    float4 bc  = *(const float4*)&biasC[c];
    acc.x += bc.x; acc.y += bc.y; acc.z += bc.z; acc.w += bc.w;

    int p = o0;
    for (; p + 4 <= o1; p += 4) {
        uint2 kv0 = kb[p+0], kv1 = kb[p+1], kv2 = kb[p+2], kv3 = kb[p+3];
        uint2 g0 = *(const uint2*)&BnB[(size_t)(kv0.x & 0xFFFFF)*D + c];
        uint2 g1 = *(const uint2*)&BnB[(size_t)(kv1.x & 0xFFFFF)*D + c];
        uint2 g2 = *(const uint2*)&BnB[(size_t)(kv2.x & 0xFFFFF)*D + c];
        uint2 g3 = *(const uint2*)&BnB[(size_t)(kv3.x & 0xFFFFF)*D + c];
        float4 r0 = *(const float4*)&Rm[(kv0.x >> 20)*D + c];
        float4 r1 = *(const float4*)&Rm[(kv1.x >> 20)*D + c];
        float4 r2 = *(const float4*)&Rm[(kv2.x >> 20)*D + c];
        float4 r3 = *(const float4*)&Rm[(kv3.x >> 20)*D + c];
        float a0 = __uint_as_float(kv0.y) * inv;
        float a1 = __uint_as_float(kv1.y) * inv;
        float a2 = __uint_as_float(kv2.y) * inv;
        float a3 = __uint_as_float(kv3.y) * inv;
        acc.x += a0*(bf2f_hi(g0.x << 16)         + r0.x)
               + a1*(bf2f_hi(g1.x << 16)         + r1.x)
               + a2*(bf2f_hi(g2.x << 16)         + r2.x)
               + a3*(bf2f_hi(g3.x << 16)         + r3.x);
        acc.y += a0*(bf2f_hi(g0.x & 0xFFFF0000u) + r0.y)
               + a1*(bf2f_hi(g1.x & 0xFFFF0000u) + r1.y)
               + a2*(bf2f_hi(g2.x & 0xFFFF0000u) + r2.y)
               + a3*(bf2f_hi(g3.x & 0xFFFF0000u) + r3.y);
        acc.z += a0*(bf2f_hi(g0.y << 16)         + r0.z)
               + a1*(bf2f_hi(g1.y << 16)         + r1.z)
               + a2*(bf2f_hi(g2.y << 16)         + r2.z)
               + a3*(bf2f_hi(g3.y << 16)         + r3.z);
        acc.w += a0*(bf2f_hi(g0.y & 0xFFFF0000u) + r0.w)
               + a1*(bf2f_hi(g1.y & 0xFFFF0000u) + r1.w)
               + a2*(bf2f_hi(g2.y & 0xFFFF0000u) + r2.w)
               + a3*(bf2f_hi(g3.y & 0xFFFF0000u) + r3.w);
    }
    for (; p < o1; ++p) {
        uint2 kv = kb[p];
        float al = __uint_as_float(kv.y) * inv;
        uint2 braw = *(const uint2*)&BnB[(size_t)(kv.x & 0xFFFFF)*D + c];
        float4 rv  = *(const float4*)&Rm[(kv.x >> 20)*D + c];
        acc.x += al*(bf2f_hi(braw.x << 16)         + rv.x);
        acc.y += al*(bf2f_hi(braw.x & 0xFFFF0000u) + rv.y);
        acc.z += al*(bf2f_hi(braw.y << 16)         + rv.z);
        acc.w += al*(bf2f_hi(braw.y & 0xFFFF0000u) + rv.w);
    }
    *(float4*)&h[(size_t)n*D + c] = acc;
}

extern "C" void kernel_launch(void* const* d_in, const int* in_sizes, int n_in,
                              void* d_out, int out_size, void* d_ws, size_t ws_size,
                              hipStream_t stream) {
    const int*   trip   = (const int*)  d_in[0];
    const float* ent    = (const float*)d_in[1];
    const float* relE   = (const float*)d_in[2];
    const float* W_ent  = (const float*)d_in[3];
    const float* b_ent  = (const float*)d_in[4];
    const float* W_rel  = (const float*)d_in[5];
    const float* b_rel  = (const float*)d_in[6];
    const float* W_ent2 = (const float*)d_in[7];
    const float* b_ent2 = (const float*)d_in[8];
    const float* a_w    = (const float*)d_in[9];
    const float* a_b    = (const float*)d_in[10];
    float* h = (float*)d_out;

    // Workspace: ~31.5 MB total (proven-safe ceiling is round 4's 57.6 MB;
    // round 3's 83.26 MB overran d_ws — keep footprint well below).
    char* ws = (char*)d_ws;
    size_t o = 0;
    auto alloc = [&](size_t bytes) { size_t p = o; o += (bytes + 255) & ~(size_t)255; return p; };
    float*  WR     = (float*) (ws + alloc(128*128*4));
    ushort* WfTb   = (ushort*)(ws + alloc(256*128*2));
    float*  biasC  = (float*) (ws + alloc(128*4));
    float*  Rm     = (float*) (ws + alloc((size_t)N_RELS_C*128*4));
    float*  sR     = (float*) (ws + alloc(N_RELS_C*4));
    float*  sConst = (float*) (ws + alloc(4));
    float*  sA     = (float*) (ws + alloc((size_t)N_NODES_C*4));
    float*  sB     = (float*) (ws + alloc((size_t)N_NODES_C*4));
    int*    deg    = (int*)   (ws + alloc((size_t)N_NODES_C*4));
    int*    off    = (int*)   (ws + alloc(((size_t)N_NODES_C+1)*4));
    int*    cursor = (int*)   (ws + alloc((size_t)N_NODES_C*4));
    int*    bsum   = (int*)   (ws + alloc(128*4));
    uint2*  kb     = (uint2*) (ws + alloc((size_t)N_EDGES_C*8));
    ushort* BnB    = (ushort*)(ws + alloc((size_t)N_PAD_C*128*2));

    hipMemsetAsync(deg, 0, (size_t)N_NODES_C*4, stream);

    k_fuse_w<<<dim3(128,4), 128, 0, stream>>>(W_ent, W_rel, W_ent2, b_ent, b_rel, b_ent2,
                                              WR, WfTb, biasC);
    k_rel_scalars<<<N_RELS_C+1, 128, 0, stream>>>(relE, a_w, a_b, WR, biasC,
                                                  Rm, sR, sConst);
    k1_mfma<<<N_PAD_C/128, 256, 0, stream>>>(ent, WfTb, a_w, h, BnB, sA, sB, N_NODES_C);
    k_hist<<<(N_EDGES_C+255)/256, 256, 0, stream>>>(trip, deg, N_EDGES_C);
    int nb = (N_NODES_C + 1023)/1024;   // 98
    k_scan1<<<nb, 1024, 0, stream>>>(deg, off, bsum, N_NODES_C);
    k_scan2<<<1, 128, 0, stream>>>(bsum, nb);
    k_scan3<<<nb, 1024, 0, stream>>>(off, cursor, bsum, N_NODES_C, N_EDGES_C);
    k_edge_b<<<(N_EDGES_C+255)/256, 256, 0, stream>>>(trip, sA, sB, sR, sConst,
                                                      cursor, kb, N_EDGES_C);
    k_aggregate<<<(N_NODES_C+7)/8, 256, 0, stream>>>(off, kb, BnB, Rm, biasC,
                                                     h, N_NODES_C);
}

// Round 7
// 248.219 us; speedup vs baseline: 1.8992x; 1.0360x over previous
//
#include <hip/hip_runtime.h>
#include <hip/hip_bf16.h>

#define N_NODES_C 100000
#define N_PAD_C   100096   // padded to multiple of 128 for k1 tiles
#define N_RELS_C  237
#define N_EDGES_C 500000
#define D 128

typedef __attribute__((ext_vector_type(8))) short short8;
typedef __attribute__((ext_vector_type(4))) float f32x4;

__device__ __forceinline__ ushort f2bf(float x) {
    union { float f; uint u; } v; v.f = x;
    uint r = v.u + 0x7FFFu + ((v.u >> 16) & 1u);   // RNE
    return (ushort)(r >> 16);
}
__device__ __forceinline__ float bf2f_hi(uint u) {  // bits already in high half
    union { uint u; float f; } v; v.u = u; return v.f;
}

// ============ K0: fuse weights =============
// WfTb[j][k]   (j<128)  = sum_i W_ent[k][i] * W_ent2[i][j]      (A path, bf16, transposed)
// WfTb[128+j][k]        = sum_i W_ent[k][i] * W_ent2[128+i][j]  (B path)
// WR[k][j]              = sum_i W_rel[k][i] * W_ent2[256+i][j]
// biasC[j] = b_ent@(W1+W2) + b_rel@W3 + b_ent2
__global__ void k_fuse_w(const float* __restrict__ W_ent, const float* __restrict__ W_rel,
                         const float* __restrict__ W_ent2,
                         const float* __restrict__ b_ent, const float* __restrict__ b_rel,
                         const float* __restrict__ b_ent2,
                         float* __restrict__ WR, ushort* __restrict__ WfTb,
                         float* __restrict__ biasC) {
    int j = threadIdx.x;       // 0..127 output col
    int k = blockIdx.x;        // 0..127 row
    int which = blockIdx.y;    // 0..3
    if (which == 0) {
        float acc = 0.f;
        for (int i = 0; i < D; ++i) acc += W_ent[k*D+i] * W_ent2[i*D+j];
        WfTb[j*D + k] = f2bf(acc);
    } else if (which == 1) {
        float acc = 0.f;
        for (int i = 0; i < D; ++i) acc += W_ent[k*D+i] * W_ent2[(D+i)*D+j];
        WfTb[(D+j)*D + k] = f2bf(acc);
    } else if (which == 2) {
        float acc = 0.f;
        for (int i = 0; i < D; ++i) acc += W_rel[k*D+i] * W_ent2[(2*D+i)*D+j];
        WR[k*D + j] = acc;
    } else if (k == 0) {
        float acc = b_ent2[j];
        for (int i = 0; i < D; ++i) {
            acc += b_ent[i] * (W_ent2[i*D+j] + W_ent2[(D+i)*D+j]);
            acc += b_rel[i] * W_ent2[(2*D+i)*D+j];
        }
        biasC[j] = acc;
    }
}

// ============ K0b: relation table + rel/const attention scalars =============
__global__ void k_rel_scalars(const float* __restrict__ rel_embed,
                              const float* __restrict__ a_w, const float* __restrict__ a_b,
                              const float* __restrict__ WR, const float* __restrict__ biasC,
                              float* __restrict__ Rm, float* __restrict__ sR,
                              float* __restrict__ sConst) {
    int j = threadIdx.x;   // 128 threads
    int b = blockIdx.x;    // 0..237
    __shared__ float red[128];
    if (b < N_RELS_C) {
        float acc = 0.f;
        for (int k = 0; k < D; ++k) acc += rel_embed[b*D+k] * WR[k*D+j];
        Rm[b*D+j] = acc;
        red[j] = acc * a_w[j];
        __syncthreads();
        for (int s = 64; s > 0; s >>= 1) { if (j < s) red[j] += red[j+s]; __syncthreads(); }
        if (j == 0) sR[b] = red[0];
    } else {
        red[j] = biasC[j] * a_w[j];
        __syncthreads();
        for (int s = 64; s > 0; s >>= 1) { if (j < s) red[j] += red[j+s]; __syncthreads(); }
        if (j == 0) sConst[0] = red[0] + a_b[0];
    }
}

// ============ K1: MFMA node GEMM + fused prep =============
// [An|Bn] = ent(fp32 -> bf16 in-register) @ WfT(256x128 bf16), fp32 acc.
// 512-thread block = 8 waves: waves 0-3 -> A-half, waves 4-7 -> B-half, same
// 128 rows (paired waves load identical ent rows -> L1 dedupe). Per-wave
// acc[2][8] = 64 VGPRs; __launch_bounds__(512,4) caps VGPR at 128 -> 16 waves/CU
// with the 64 KB W LDS (2 blocks/CU). Single __syncthreads after staging.
// Outputs: AnB bf16, BnB bf16, and fused sA/sB = (A|B)@a_w.
__global__ __launch_bounds__(512, 4) void k1_mfma(const float* __restrict__ ent,
                                                  const ushort* __restrict__ WfTb,
                                                  const float* __restrict__ a_w,
                                                  ushort* __restrict__ AnB,
                                                  ushort* __restrict__ BnB,
                                                  float* __restrict__ sA,
                                                  float* __restrict__ sB,
                                                  int n_nodes) {
    __shared__ __align__(16) ushort wL[256*128];   // 64 KB, both halves
    int tid = threadIdx.x;
    int m0 = blockIdx.x * 128;

    // stage W: 256 rows x 16 (16B units), swizzled unit col = k16 ^ (r&15)
#pragma unroll
    for (int u = 0; u < 8; ++u) {
        int f = u*512 + tid;          // 0..4095
        int r = f >> 4, k16 = f & 15;
        *(uint4*)&wL[r*128 + ((k16 ^ (r & 15)) << 3)] =
            *(const uint4*)&WfTb[r*128 + (k16 << 3)];
    }
    __syncthreads();

    int wave = tid >> 6, lane = tid & 63;
    int ny = wave >> 2;                 // 0 = A-half, 1 = B-half
    int q = lane >> 4, c = lane & 15;
    int wm = (wave & 3) * 32;           // 4 row-tiles x 32 rows = 128 rows

    f32x4 acc[2][8];
#pragma unroll
    for (int mt = 0; mt < 2; ++mt)
#pragma unroll
        for (int nt = 0; nt < 8; ++nt) { f32x4 z = {0.f,0.f,0.f,0.f}; acc[mt][nt] = z; }

#pragma unroll
    for (int chunk = 0; chunk < 4; ++chunk) {
        int k16 = chunk*4 + q;
        short8 a[2];
#pragma unroll
        for (int mt = 0; mt < 2; ++mt) {
            int row = m0 + wm + mt*16 + c;
            float4 e0 = make_float4(0.f,0.f,0.f,0.f), e1 = e0;
            if (row < n_nodes) {
                const float* ep = &ent[(size_t)row*D + (k16 << 3)];
                e0 = *(const float4*)ep;
                e1 = *(const float4*)(ep + 4);
            }
            short8 pk;
            pk[0]=(short)f2bf(e0.x); pk[1]=(short)f2bf(e0.y); pk[2]=(short)f2bf(e0.z); pk[3]=(short)f2bf(e0.w);
            pk[4]=(short)f2bf(e1.x); pk[5]=(short)f2bf(e1.y); pk[6]=(short)f2bf(e1.z); pk[7]=(short)f2bf(e1.w);
            a[mt] = pk;
        }
#pragma unroll
        for (int nt = 0; nt < 8; ++nt) {
            int wrow = ny*128 + nt*16 + c;     // wrow&15 == c
            short8 b = *(const short8*)&wL[wrow*128 + ((k16 ^ c) << 3)];
            acc[0][nt] = __builtin_amdgcn_mfma_f32_16x16x32_bf16(a[0], b, acc[0][nt], 0, 0, 0);
            acc[1][nt] = __builtin_amdgcn_mfma_f32_16x16x32_bf16(a[1], b, acc[1][nt], 0, 0, 0);
        }
    }

    // a_w values this lane needs for the sA/sB reduction: col = nt*16 + c
    float aw[8];
#pragma unroll
    for (int nt = 0; nt < 8; ++nt) aw[nt] = a_w[nt*16 + c];

    ushort* out  = ny ? BnB : AnB;
    float*  sOut = ny ? sB  : sA;

    // epilogue: C/D layout col=lane&15, row=q*4+reg
#pragma unroll
    for (int mt = 0; mt < 2; ++mt) {
#pragma unroll
        for (int reg = 0; reg < 4; ++reg) {
            int m = m0 + wm + mt*16 + q*4 + reg;
            float pa = 0.f;
#pragma unroll
            for (int nt = 0; nt < 8; ++nt) pa += acc[mt][nt][reg] * aw[nt];
#pragma unroll
            for (int msk = 1; msk < 16; msk <<= 1) pa += __shfl_xor(pa, msk);
            if (m < n_nodes) {
                if (c == 0) sOut[m] = pa;
#pragma unroll
                for (int nt = 0; nt < 8; ++nt)
                    out[(size_t)m*D + nt*16 + c] = f2bf(acc[mt][nt][reg]);
            }
        }
    }
}

// ============ K2: CSR build =============
__global__ void k_hist(const int* __restrict__ trip, int* __restrict__ deg, int n_edges) {
    int e = blockIdx.x*256 + threadIdx.x;
    if (e >= n_edges) return;
    int s = trip[3*e];
    if ((unsigned)s >= (unsigned)N_NODES_C) return;   // guard (no-op on valid input)
    atomicAdd(&deg[s], 1);
}

// hierarchical 3-kernel scan (round-4 proven: coalesced, ~5 us combined)
__global__ void k_scan1(const int* __restrict__ deg, int* __restrict__ off,
                        int* __restrict__ bsum, int n) {
    __shared__ int s[1024];
    int i = blockIdx.x*1024 + threadIdx.x;
    int v = (i < n) ? deg[i] : 0;
    s[threadIdx.x] = v; __syncthreads();
    for (int d = 1; d < 1024; d <<= 1) {
        int t = (threadIdx.x >= d) ? s[threadIdx.x - d] : 0;
        __syncthreads();
        s[threadIdx.x] += t;
        __syncthreads();
    }
    if (i < n) off[i] = s[threadIdx.x] - v;          // exclusive, pre-block-offset
    if (threadIdx.x == 1023) bsum[blockIdx.x] = s[1023];
}

__global__ void k_scan2(int* __restrict__ bsum, int nb) {
    __shared__ int s[128];
    int v = (threadIdx.x < nb) ? bsum[threadIdx.x] : 0;
    s[threadIdx.x] = v; __syncthreads();
    for (int d = 1; d < 128; d <<= 1) {
        int t = (threadIdx.x >= d) ? s[threadIdx.x - d] : 0;
        __syncthreads();
        s[threadIdx.x] += t;
        __syncthreads();
    }
    if (threadIdx.x < nb) bsum[threadIdx.x] = s[threadIdx.x] - v;  // exclusive, in-place
}

__global__ void k_scan3(int* __restrict__ off, int* __restrict__ cursor,
                        const int* __restrict__ bsum, int n, int total_edges) {
    int i = blockIdx.x*1024 + threadIdx.x;
    if (i < n) {
        int o = off[i] + bsum[blockIdx.x];
        off[i] = o;
        cursor[i] = o;
    }
    if (i == 0) off[n] = total_edges;
}

// ============ K2c: per-edge b + scatter combined (key,b) record into CSR slot ======
__global__ void k_edge_b(const int* __restrict__ trip, const float* __restrict__ sA,
                         const float* __restrict__ sB, const float* __restrict__ sR,
                         const float* __restrict__ sConst, int* __restrict__ cursor,
                         uint2* __restrict__ kb, int n_edges) {
    int e = blockIdx.x*256 + threadIdx.x;
    if (e >= n_edges) return;
    int s = trip[3*e], d = trip[3*e+1], r = trip[3*e+2];
    if ((unsigned)s >= (unsigned)N_NODES_C || (unsigned)d >= (unsigned)N_NODES_C ||
        (unsigned)r >= (unsigned)N_RELS_C) return;   // guard (matches k_hist)
    float logit = sA[s] + sB[d] + sR[r] + sConst[0];
    float l = logit > 0.f ? logit : 0.01f*logit;
    float b = expf(l);
    int p = atomicAdd(&cursor[s], 1);
    kb[p] = make_uint2((uint)(d | (r << 20)), __float_as_uint(b));
}

// ============ K3: node-major aggregation (no atomics), unroll-4 gathers =============
// h[n] = An[n] + biasC + sum alpha*(B[dst]+R[rel]); An read from AnB (bf16),
// h is write-only here; zero-degree nodes get 0 (segment_sum over empty set).
__global__ void k_aggregate(const int* __restrict__ off, const uint2* __restrict__ kb,
                            const ushort* __restrict__ AnB, const ushort* __restrict__ BnB,
                            const float* __restrict__ Rm, const float* __restrict__ biasC,
                            float* __restrict__ h, int n_nodes) {
    int g = threadIdx.x >> 5, lane = threadIdx.x & 31;
    int n = blockIdx.x*8 + g;
    if (n >= n_nodes) return;
    int o0 = off[n], o1 = off[n+1];
    int c = lane*4;
    if (o0 == o1) {
        *(float4*)&h[(size_t)n*D + c] = make_float4(0.f,0.f,0.f,0.f);
        return;
    }
    float s = 0.f;
    for (int p = o0 + lane; p < o1; p += 32) s += __uint_as_float(kb[p].y);
    for (int m = 16; m > 0; m >>= 1) s += __shfl_xor(s, m, 32);
    float inv = 1.f / s;
    uint2 araw = *(const uint2*)&AnB[(size_t)n*D + c];
    float4 bc  = *(const float4*)&biasC[c];
    float4 acc;
    acc.x = bf2f_hi(araw.x << 16)         + bc.x;
    acc.y = bf2f_hi(araw.x & 0xFFFF0000u) + bc.y;
    acc.z = bf2f_hi(araw.y << 16)         + bc.z;
    acc.w = bf2f_hi(araw.y & 0xFFFF0000u) + bc.w;

    int p = o0;
    for (; p + 4 <= o1; p += 4) {
        uint2 kv0 = kb[p+0], kv1 = kb[p+1], kv2 = kb[p+2], kv3 = kb[p+3];
        uint2 g0 = *(const uint2*)&BnB[(size_t)(kv0.x & 0xFFFFF)*D + c];
        uint2 g1 = *(const uint2*)&BnB[(size_t)(kv1.x & 0xFFFFF)*D + c];
        uint2 g2 = *(const uint2*)&BnB[(size_t)(kv2.x & 0xFFFFF)*D + c];
        uint2 g3 = *(const uint2*)&BnB[(size_t)(kv3.x & 0xFFFFF)*D + c];
        float4 r0 = *(const float4*)&Rm[(kv0.x >> 20)*D + c];
        float4 r1 = *(const float4*)&Rm[(kv1.x >> 20)*D + c];
        float4 r2 = *(const float4*)&Rm[(kv2.x >> 20)*D + c];
        float4 r3 = *(const float4*)&Rm[(kv3.x >> 20)*D + c];
        float a0 = __uint_as_float(kv0.y) * inv;
        float a1 = __uint_as_float(kv1.y) * inv;
        float a2 = __uint_as_float(kv2.y) * inv;
        float a3 = __uint_as_float(kv3.y) * inv;
        acc.x += a0*(bf2f_hi(g0.x << 16)         + r0.x)
               + a1*(bf2f_hi(g1.x << 16)         + r1.x)
               + a2*(bf2f_hi(g2.x << 16)         + r2.x)
               + a3*(bf2f_hi(g3.x << 16)         + r3.x);
        acc.y += a0*(bf2f_hi(g0.x & 0xFFFF0000u) + r0.y)
               + a1*(bf2f_hi(g1.x & 0xFFFF0000u) + r1.y)
               + a2*(bf2f_hi(g2.x & 0xFFFF0000u) + r2.y)
               + a3*(bf2f_hi(g3.x & 0xFFFF0000u) + r3.y);
        acc.z += a0*(bf2f_hi(g0.y << 16)         + r0.z)
               + a1*(bf2f_hi(g1.y << 16)         + r1.z)
               + a2*(bf2f_hi(g2.y << 16)         + r2.z)
               + a3*(bf2f_hi(g3.y << 16)         + r3.z);
        acc.w += a0*(bf2f_hi(g0.y & 0xFFFF0000u) + r0.w)
               + a1*(bf2f_hi(g1.y & 0xFFFF0000u) + r1.w)
               + a2*(bf2f_hi(g2.y & 0xFFFF0000u) + r2.w)
               + a3*(bf2f_hi(g3.y & 0xFFFF0000u) + r3.w);
    }
    for (; p < o1; ++p) {
        uint2 kv = kb[p];
        float al = __uint_as_float(kv.y) * inv;
        uint2 braw = *(const uint2*)&BnB[(size_t)(kv.x & 0xFFFFF)*D + c];
        float4 rv  = *(const float4*)&Rm[(kv.x >> 20)*D + c];
        acc.x += al*(bf2f_hi(braw.x << 16)         + rv.x);
        acc.y += al*(bf2f_hi(braw.x & 0xFFFF0000u) + rv.y);
        acc.z += al*(bf2f_hi(braw.y << 16)         + rv.z);
        acc.w += al*(bf2f_hi(braw.y & 0xFFFF0000u) + rv.w);
    }
    *(float4*)&h[(size_t)n*D + c] = acc;
}

extern "C" void kernel_launch(void* const* d_in, const int* in_sizes, int n_in,
                              void* d_out, int out_size, void* d_ws, size_t ws_size,
                              hipStream_t stream) {
    const int*   trip   = (const int*)  d_in[0];
    const float* ent    = (const float*)d_in[1];
    const float* relE   = (const float*)d_in[2];
    const float* W_ent  = (const float*)d_in[3];
    const float* b_ent  = (const float*)d_in[4];
    const float* W_rel  = (const float*)d_in[5];
    const float* b_rel  = (const float*)d_in[6];
    const float* W_ent2 = (const float*)d_in[7];
    const float* b_ent2 = (const float*)d_in[8];
    const float* a_w    = (const float*)d_in[9];
    const float* a_b    = (const float*)d_in[10];
    float* h = (float*)d_out;

    // Workspace: ~57.1 MB total — stays under round 4's proven-safe 57.6 MB
    // (round 3's 83.26 MB overran d_ws and corrupted harness state).
    char* ws = (char*)d_ws;
    size_t o = 0;
    auto alloc = [&](size_t bytes) { size_t p = o; o += (bytes + 255) & ~(size_t)255; return p; };
    float*  WR     = (float*) (ws + alloc(128*128*4));
    ushort* WfTb   = (ushort*)(ws + alloc(256*128*2));
    float*  biasC  = (float*) (ws + alloc(128*4));
    float*  Rm     = (float*) (ws + alloc((size_t)N_RELS_C*128*4));
    float*  sR     = (float*) (ws + alloc(N_RELS_C*4));
    float*  sConst = (float*) (ws + alloc(4));
    float*  sA     = (float*) (ws + alloc((size_t)N_NODES_C*4));
    float*  sB     = (float*) (ws + alloc((size_t)N_NODES_C*4));
    int*    deg    = (int*)   (ws + alloc((size_t)N_NODES_C*4));
    int*    off    = (int*)   (ws + alloc(((size_t)N_NODES_C+1)*4));
    int*    cursor = (int*)   (ws + alloc((size_t)N_NODES_C*4));
    int*    bsum   = (int*)   (ws + alloc(128*4));
    uint2*  kb     = (uint2*) (ws + alloc((size_t)N_EDGES_C*8));
    ushort* BnB    = (ushort*)(ws + alloc((size_t)N_PAD_C*128*2));
    ushort* AnB    = (ushort*)(ws + alloc((size_t)N_PAD_C*128*2));

    hipMemsetAsync(deg, 0, (size_t)N_NODES_C*4, stream);

    k_fuse_w<<<dim3(128,4), 128, 0, stream>>>(W_ent, W_rel, W_ent2, b_ent, b_rel, b_ent2,
                                              WR, WfTb, biasC);
    k_rel_scalars<<<N_RELS_C+1, 128, 0, stream>>>(relE, a_w, a_b, WR, biasC,
                                                  Rm, sR, sConst);
    k1_mfma<<<N_PAD_C/128, 512, 0, stream>>>(ent, WfTb, a_w, AnB, BnB, sA, sB, N_NODES_C);
    k_hist<<<(N_EDGES_C+255)/256, 256, 0, stream>>>(trip, deg, N_EDGES_C);
    int nb = (N_NODES_C + 1023)/1024;   // 98
    k_scan1<<<nb, 1024, 0, stream>>>(deg, off, bsum, N_NODES_C);
    k_scan2<<<1, 128, 0, stream>>>(bsum, nb);
    k_scan3<<<nb, 1024, 0, stream>>>(off, cursor, bsum, N_NODES_C, N_EDGES_C);
    k_edge_b<<<(N_EDGES_C+255)/256, 256, 0, stream>>>(trip, sA, sB, sR, sConst,
                                                      cursor, kb, N_EDGES_C);
    k_aggregate<<<(N_NODES_C+7)/8, 256, 0, stream>>>(off, kb, AnB, BnB, Rm, biasC,
                                                     h, N_NODES_C);
}

// Round 8
// 244.607 us; speedup vs baseline: 1.9273x; 1.0148x over previous
//
#include <hip/hip_runtime.h>
#include <hip/hip_bf16.h>

#define N_NODES_C 100000
#define N_PAD_C   100096   // padded to multiple of 128 for k1 tiles
#define N_RELS_C  237
#define N_EDGES_C 500000
#define D 128

typedef __attribute__((ext_vector_type(8))) short short8;
typedef __attribute__((ext_vector_type(4))) float f32x4;

__device__ __forceinline__ ushort f2bf(float x) {
    union { float f; uint u; } v; v.f = x;
    uint r = v.u + 0x7FFFu + ((v.u >> 16) & 1u);   // RNE
    return (ushort)(r >> 16);
}
__device__ __forceinline__ float bf2f_hi(uint u) {  // bits already in high half
    union { uint u; float f; } v; v.u = u; return v.f;
}

// ============ K0: fuse weights =============
// WfTb[j][k]   (j<128)  = sum_i W_ent[k][i] * W_ent2[i][j]      (A path, bf16, transposed)
// WfTb[128+j][k]        = sum_i W_ent[k][i] * W_ent2[128+i][j]  (B path)
// WR[k][j]              = sum_i W_rel[k][i] * W_ent2[256+i][j]
// biasC[j] = b_ent@(W1+W2) + b_rel@W3 + b_ent2
__global__ void k_fuse_w(const float* __restrict__ W_ent, const float* __restrict__ W_rel,
                         const float* __restrict__ W_ent2,
                         const float* __restrict__ b_ent, const float* __restrict__ b_rel,
                         const float* __restrict__ b_ent2,
                         float* __restrict__ WR, ushort* __restrict__ WfTb,
                         float* __restrict__ biasC) {
    int j = threadIdx.x;       // 0..127 output col
    int k = blockIdx.x;        // 0..127 row
    int which = blockIdx.y;    // 0..3
    if (which == 0) {
        float acc = 0.f;
        for (int i = 0; i < D; ++i) acc += W_ent[k*D+i] * W_ent2[i*D+j];
        WfTb[j*D + k] = f2bf(acc);
    } else if (which == 1) {
        float acc = 0.f;
        for (int i = 0; i < D; ++i) acc += W_ent[k*D+i] * W_ent2[(D+i)*D+j];
        WfTb[(D+j)*D + k] = f2bf(acc);
    } else if (which == 2) {
        float acc = 0.f;
        for (int i = 0; i < D; ++i) acc += W_rel[k*D+i] * W_ent2[(2*D+i)*D+j];
        WR[k*D + j] = acc;
    } else if (k == 0) {
        float acc = b_ent2[j];
        for (int i = 0; i < D; ++i) {
            acc += b_ent[i] * (W_ent2[i*D+j] + W_ent2[(D+i)*D+j]);
            acc += b_rel[i] * W_ent2[(2*D+i)*D+j];
        }
        biasC[j] = acc;
    }
}

// ============ K0b: relation table (bf16) + rel/const attention scalars =============
__global__ void k_rel_scalars(const float* __restrict__ rel_embed,
                              const float* __restrict__ a_w, const float* __restrict__ a_b,
                              const float* __restrict__ WR, const float* __restrict__ biasC,
                              ushort* __restrict__ RmB, float* __restrict__ sR,
                              float* __restrict__ sConst) {
    int j = threadIdx.x;   // 128 threads
    int b = blockIdx.x;    // 0..237
    __shared__ float red[128];
    if (b < N_RELS_C) {
        float acc = 0.f;
        for (int k = 0; k < D; ++k) acc += rel_embed[b*D+k] * WR[k*D+j];
        RmB[b*D+j] = f2bf(acc);
        red[j] = acc * a_w[j];
        __syncthreads();
        for (int s = 64; s > 0; s >>= 1) { if (j < s) red[j] += red[j+s]; __syncthreads(); }
        if (j == 0) sR[b] = red[0];
    } else {
        red[j] = biasC[j] * a_w[j];
        __syncthreads();
        for (int s = 64; s > 0; s >>= 1) { if (j < s) red[j] += red[j+s]; __syncthreads(); }
        if (j == 0) sConst[0] = red[0] + a_b[0];
    }
}

// ============ K1: MFMA node GEMM + fused prep =============
// [An|Bn] = ent(fp32 -> bf16 in-register) @ WfT(256x128 bf16), fp32 acc.
// 512-thread block = 8 waves: waves 0-3 -> A-half, waves 4-7 -> B-half, same
// 128 rows (paired waves load identical ent rows -> L1 dedupe). Per-wave
// acc[2][8] = 64 VGPRs; __launch_bounds__(512,4) caps VGPR at 128 -> 16 waves/CU
// with the 64 KB W LDS (2 blocks/CU). Single __syncthreads after staging.
// Outputs: AnB bf16, BnB bf16, and fused sA/sB = (A|B)@a_w.
__global__ __launch_bounds__(512, 4) void k1_mfma(const float* __restrict__ ent,
                                                  const ushort* __restrict__ WfTb,
                                                  const float* __restrict__ a_w,
                                                  ushort* __restrict__ AnB,
                                                  ushort* __restrict__ BnB,
                                                  float* __restrict__ sA,
                                                  float* __restrict__ sB,
                                                  int n_nodes) {
    __shared__ __align__(16) ushort wL[256*128];   // 64 KB, both halves
    int tid = threadIdx.x;
    int m0 = blockIdx.x * 128;

    // stage W: 256 rows x 16 (16B units), swizzled unit col = k16 ^ (r&15)
#pragma unroll
    for (int u = 0; u < 8; ++u) {
        int f = u*512 + tid;          // 0..4095
        int r = f >> 4, k16 = f & 15;
        *(uint4*)&wL[r*128 + ((k16 ^ (r & 15)) << 3)] =
            *(const uint4*)&WfTb[r*128 + (k16 << 3)];
    }
    __syncthreads();

    int wave = tid >> 6, lane = tid & 63;
    int ny = wave >> 2;                 // 0 = A-half, 1 = B-half
    int q = lane >> 4, c = lane & 15;
    int wm = (wave & 3) * 32;           // 4 row-tiles x 32 rows = 128 rows

    f32x4 acc[2][8];
#pragma unroll
    for (int mt = 0; mt < 2; ++mt)
#pragma unroll
        for (int nt = 0; nt < 8; ++nt) { f32x4 z = {0.f,0.f,0.f,0.f}; acc[mt][nt] = z; }

#pragma unroll
    for (int chunk = 0; chunk < 4; ++chunk) {
        int k16 = chunk*4 + q;
        short8 a[2];
#pragma unroll
        for (int mt = 0; mt < 2; ++mt) {
            int row = m0 + wm + mt*16 + c;
            float4 e0 = make_float4(0.f,0.f,0.f,0.f), e1 = e0;
            if (row < n_nodes) {
                const float* ep = &ent[(size_t)row*D + (k16 << 3)];
                e0 = *(const float4*)ep;
                e1 = *(const float4*)(ep + 4);
            }
            short8 pk;
            pk[0]=(short)f2bf(e0.x); pk[1]=(short)f2bf(e0.y); pk[2]=(short)f2bf(e0.z); pk[3]=(short)f2bf(e0.w);
            pk[4]=(short)f2bf(e1.x); pk[5]=(short)f2bf(e1.y); pk[6]=(short)f2bf(e1.z); pk[7]=(short)f2bf(e1.w);
            a[mt] = pk;
        }
#pragma unroll
        for (int nt = 0; nt < 8; ++nt) {
            int wrow = ny*128 + nt*16 + c;     // wrow&15 == c
            short8 b = *(const short8*)&wL[wrow*128 + ((k16 ^ c) << 3)];
            acc[0][nt] = __builtin_amdgcn_mfma_f32_16x16x32_bf16(a[0], b, acc[0][nt], 0, 0, 0);
            acc[1][nt] = __builtin_amdgcn_mfma_f32_16x16x32_bf16(a[1], b, acc[1][nt], 0, 0, 0);
        }
    }

    // a_w values this lane needs for the sA/sB reduction: col = nt*16 + c
    float aw[8];
#pragma unroll
    for (int nt = 0; nt < 8; ++nt) aw[nt] = a_w[nt*16 + c];

    ushort* out  = ny ? BnB : AnB;
    float*  sOut = ny ? sB  : sA;

    // epilogue: C/D layout col=lane&15, row=q*4+reg
#pragma unroll
    for (int mt = 0; mt < 2; ++mt) {
#pragma unroll
        for (int reg = 0; reg < 4; ++reg) {
            int m = m0 + wm + mt*16 + q*4 + reg;
            float pa = 0.f;
#pragma unroll
            for (int nt = 0; nt < 8; ++nt) pa += acc[mt][nt][reg] * aw[nt];
#pragma unroll
            for (int msk = 1; msk < 16; msk <<= 1) pa += __shfl_xor(pa, msk);
            if (m < n_nodes) {
                if (c == 0) sOut[m] = pa;
#pragma unroll
                for (int nt = 0; nt < 8; ++nt)
                    out[(size_t)m*D + nt*16 + c] = f2bf(acc[mt][nt][reg]);
            }
        }
    }
}

// ============ K2: CSR build =============
__global__ void k_hist(const int* __restrict__ trip, int* __restrict__ deg, int n_edges) {
    int e = blockIdx.x*256 + threadIdx.x;
    if (e >= n_edges) return;
    int s = trip[3*e];
    if ((unsigned)s >= (unsigned)N_NODES_C) return;   // guard (no-op on valid input)
    atomicAdd(&deg[s], 1);
}

// hierarchical 3-kernel scan (round-4 proven: coalesced, ~5 us combined)
__global__ void k_scan1(const int* __restrict__ deg, int* __restrict__ off,
                        int* __restrict__ bsum, int n) {
    __shared__ int s[1024];
    int i = blockIdx.x*1024 + threadIdx.x;
    int v = (i < n) ? deg[i] : 0;
    s[threadIdx.x] = v; __syncthreads();
    for (int d = 1; d < 1024; d <<= 1) {
        int t = (threadIdx.x >= d) ? s[threadIdx.x - d] : 0;
        __syncthreads();
        s[threadIdx.x] += t;
        __syncthreads();
    }
    if (i < n) off[i] = s[threadIdx.x] - v;          // exclusive, pre-block-offset
    if (threadIdx.x == 1023) bsum[blockIdx.x] = s[1023];
}

__global__ void k_scan2(int* __restrict__ bsum, int nb) {
    __shared__ int s[128];
    int v = (threadIdx.x < nb) ? bsum[threadIdx.x] : 0;
    s[threadIdx.x] = v; __syncthreads();
    for (int d = 1; d < 128; d <<= 1) {
        int t = (threadIdx.x >= d) ? s[threadIdx.x - d] : 0;
        __syncthreads();
        s[threadIdx.x] += t;
        __syncthreads();
    }
    if (threadIdx.x < nb) bsum[threadIdx.x] = s[threadIdx.x] - v;  // exclusive, in-place
}

__global__ void k_scan3(int* __restrict__ off, int* __restrict__ cursor,
                        const int* __restrict__ bsum, int n, int total_edges) {
    int i = blockIdx.x*1024 + threadIdx.x;
    if (i < n) {
        int o = off[i] + bsum[blockIdx.x];
        off[i] = o;
        cursor[i] = o;
    }
    if (i == 0) off[n] = total_edges;
}

// ============ K2c: scatter (key, sB[dst]+sR[rel]) record into CSR slot ============
// The exp moves to k_aggregate (sA[src]+const is node-uniform there), so this
// kernel no longer gathers sA nor evaluates expf.
__global__ void k_edge_b(const int* __restrict__ trip, const float* __restrict__ sB,
                         const float* __restrict__ sR, int* __restrict__ cursor,
                         uint2* __restrict__ kb, int n_edges) {
    int e = blockIdx.x*256 + threadIdx.x;
    if (e >= n_edges) return;
    int s = trip[3*e], d = trip[3*e+1], r = trip[3*e+2];
    if ((unsigned)s >= (unsigned)N_NODES_C || (unsigned)d >= (unsigned)N_NODES_C ||
        (unsigned)r >= (unsigned)N_RELS_C) return;   // guard (matches k_hist)
    float v = sB[d] + sR[r];
    int p = atomicAdd(&cursor[s], 1);
    kb[p] = make_uint2((uint)(d | (r << 20)), __float_as_uint(v));
}

// ============ K3: single-pass node-major aggregation =============
// h[n] = An[n] + biasC + num/den, num = sum_e b_e*(B[dst]+R[rel]), den = sum_e b_e,
// b_e = exp(leaky(sA[n] + v_e + const)). 16 lanes per node (4 chains/wave),
// uint4 = 8-bf16 row loads; den is lane-redundant (no cross-lane reduce).
__global__ void k_aggregate(const int* __restrict__ off, const uint2* __restrict__ kb,
                            const ushort* __restrict__ AnB, const ushort* __restrict__ BnB,
                            const ushort* __restrict__ RmB, const float* __restrict__ biasC,
                            const float* __restrict__ sA, const float* __restrict__ sConst,
                            float* __restrict__ h, int n_nodes) {
    int g = threadIdx.x >> 4, lane = threadIdx.x & 15;
    int n = blockIdx.x*16 + g;
    if (n >= n_nodes) return;
    int o0 = off[n], o1 = off[n+1];
    int c = lane*8;
    float* hp = &h[(size_t)n*D + c];
    if (o0 == o1) {
        *(float4*)hp     = make_float4(0.f,0.f,0.f,0.f);
        *(float4*)(hp+4) = make_float4(0.f,0.f,0.f,0.f);
        return;
    }
    float t = sA[n] + sConst[0];
    float num[8];
#pragma unroll
    for (int i = 0; i < 8; ++i) num[i] = 0.f;
    float den = 0.f;

    int p = o0;
    for (; p + 4 <= o1; p += 4) {
        uint2 kv[4]; uint4 gB[4], gR[4];
#pragma unroll
        for (int u = 0; u < 4; ++u) kv[u] = kb[p+u];
#pragma unroll
        for (int u = 0; u < 4; ++u) {
            gB[u] = *(const uint4*)&BnB[(size_t)(kv[u].x & 0xFFFFF)*D + c];
            gR[u] = *(const uint4*)&RmB[(size_t)(kv[u].x >> 20)*D + c];
        }
#pragma unroll
        for (int u = 0; u < 4; ++u) {
            float logit = t + __uint_as_float(kv[u].y);
            float l = logit > 0.f ? logit : 0.01f*logit;
            float b = expf(l);
            den += b;
            const uint* bu = (const uint*)&gB[u];
            const uint* ru = (const uint*)&gR[u];
#pragma unroll
            for (int i = 0; i < 4; ++i) {
                num[2*i]   += b * (bf2f_hi(bu[i] << 16)         + bf2f_hi(ru[i] << 16));
                num[2*i+1] += b * (bf2f_hi(bu[i] & 0xFFFF0000u) + bf2f_hi(ru[i] & 0xFFFF0000u));
            }
        }
    }
    for (; p < o1; ++p) {
        uint2 kv = kb[p];
        float logit = t + __uint_as_float(kv.y);
        float l = logit > 0.f ? logit : 0.01f*logit;
        float b = expf(l);
        den += b;
        uint4 gB = *(const uint4*)&BnB[(size_t)(kv.x & 0xFFFFF)*D + c];
        uint4 gR = *(const uint4*)&RmB[(size_t)(kv.x >> 20)*D + c];
        const uint* bu = (const uint*)&gB;
        const uint* ru = (const uint*)&gR;
#pragma unroll
        for (int i = 0; i < 4; ++i) {
            num[2*i]   += b * (bf2f_hi(bu[i] << 16)         + bf2f_hi(ru[i] << 16));
            num[2*i+1] += b * (bf2f_hi(bu[i] & 0xFFFF0000u) + bf2f_hi(ru[i] & 0xFFFF0000u));
        }
    }

    float inv = 1.f / den;
    uint4 araw = *(const uint4*)&AnB[(size_t)n*D + c];
    const uint* au = (const uint*)&araw;
    float4 bc0 = *(const float4*)&biasC[c];
    float4 bc1 = *(const float4*)&biasC[c+4];
    float4 o0v, o1v;
    o0v.x = bf2f_hi(au[0] << 16)         + bc0.x + num[0]*inv;
    o0v.y = bf2f_hi(au[0] & 0xFFFF0000u) + bc0.y + num[1]*inv;
    o0v.z = bf2f_hi(au[1] << 16)         + bc0.z + num[2]*inv;
    o0v.w = bf2f_hi(au[1] & 0xFFFF0000u) + bc0.w + num[3]*inv;
    o1v.x = bf2f_hi(au[2] << 16)         + bc1.x + num[4]*inv;
    o1v.y = bf2f_hi(au[2] & 0xFFFF0000u) + bc1.y + num[5]*inv;
    o1v.z = bf2f_hi(au[3] << 16)         + bc1.z + num[6]*inv;
    o1v.w = bf2f_hi(au[3] & 0xFFFF0000u) + bc1.w + num[7]*inv;
    *(float4*)hp     = o0v;
    *(float4*)(hp+4) = o1v;
}

extern "C" void kernel_launch(void* const* d_in, const int* in_sizes, int n_in,
                              void* d_out, int out_size, void* d_ws, size_t ws_size,
                              hipStream_t stream) {
    const int*   trip   = (const int*)  d_in[0];
    const float* ent    = (const float*)d_in[1];
    const float* relE   = (const float*)d_in[2];
    const float* W_ent  = (const float*)d_in[3];
    const float* b_ent  = (const float*)d_in[4];
    const float* W_rel  = (const float*)d_in[5];
    const float* b_rel  = (const float*)d_in[6];
    const float* W_ent2 = (const float*)d_in[7];
    const float* b_ent2 = (const float*)d_in[8];
    const float* a_w    = (const float*)d_in[9];
    const float* a_b    = (const float*)d_in[10];
    float* h = (float*)d_out;

    // Workspace: ~57 MB total — stays under round 4's proven-safe 57.6 MB
    // (round 3's 83.26 MB overran d_ws and corrupted harness state).
    char* ws = (char*)d_ws;
    size_t o = 0;
    auto alloc = [&](size_t bytes) { size_t p = o; o += (bytes + 255) & ~(size_t)255; return p; };
    float*  WR     = (float*) (ws + alloc(128*128*4));
    ushort* WfTb   = (ushort*)(ws + alloc(256*128*2));
    float*  biasC  = (float*) (ws + alloc(128*4));
    ushort* RmB    = (ushort*)(ws + alloc((size_t)N_RELS_C*128*2));
    float*  sR     = (float*) (ws + alloc(N_RELS_C*4));
    float*  sConst = (float*) (ws + alloc(4));
    float*  sA     = (float*) (ws + alloc((size_t)N_NODES_C*4));
    float*  sB     = (float*) (ws + alloc((size_t)N_NODES_C*4));
    int*    deg    = (int*)   (ws + alloc((size_t)N_NODES_C*4));
    int*    off    = (int*)   (ws + alloc(((size_t)N_NODES_C+1)*4));
    int*    cursor = (int*)   (ws + alloc((size_t)N_NODES_C*4));
    int*    bsum   = (int*)   (ws + alloc(128*4));
    uint2*  kb     = (uint2*) (ws + alloc((size_t)N_EDGES_C*8));
    ushort* BnB    = (ushort*)(ws + alloc((size_t)N_PAD_C*128*2));
    ushort* AnB    = (ushort*)(ws + alloc((size_t)N_PAD_C*128*2));

    hipMemsetAsync(deg, 0, (size_t)N_NODES_C*4, stream);

    k_fuse_w<<<dim3(128,4), 128, 0, stream>>>(W_ent, W_rel, W_ent2, b_ent, b_rel, b_ent2,
                                              WR, WfTb, biasC);
    k_rel_scalars<<<N_RELS_C+1, 128, 0, stream>>>(relE, a_w, a_b, WR, biasC,
                                                  RmB, sR, sConst);
    k1_mfma<<<N_PAD_C/128, 512, 0, stream>>>(ent, WfTb, a_w, AnB, BnB, sA, sB, N_NODES_C);
    k_hist<<<(N_EDGES_C+255)/256, 256, 0, stream>>>(trip, deg, N_EDGES_C);
    int nb = (N_NODES_C + 1023)/1024;   // 98
    k_scan1<<<nb, 1024, 0, stream>>>(deg, off, bsum, N_NODES_C);
    k_scan2<<<1, 128, 0, stream>>>(bsum, nb);
    k_scan3<<<nb, 1024, 0, stream>>>(off, cursor, bsum, N_NODES_C, N_EDGES_C);
    k_edge_b<<<(N_EDGES_C+255)/256, 256, 0, stream>>>(trip, sB, sR, cursor, kb, N_EDGES_C);
    k_aggregate<<<(N_NODES_C+15)/16, 256, 0, stream>>>(off, kb, AnB, BnB, RmB, biasC,
                                                       sA, sConst, h, N_NODES_C);
}